// Round 2
// baseline (650.027 us; speedup 1.0000x reference)
//
#include <hip/hip_runtime.h>

#define SS 2048
#define DD 1024
#define DQKV 3072
#define KP 1056            // 1024 + 16 lora + 1 bias + 15 pad
#define MTOT 8192
#define QKSZ ((size_t)MTOT * DD)   // floats per q/k/v plane

typedef unsigned short us;
typedef __attribute__((ext_vector_type(8))) short bf16x8;
typedef __attribute__((ext_vector_type(4))) short bf16x4v;
typedef __attribute__((ext_vector_type(4))) float f32x4;

__device__ __forceinline__ us f2bf(float f) {
    unsigned u = __float_as_uint(f);
    return (us)((u + 0x7fffu + ((u >> 16) & 1u)) >> 16);
}
__device__ __forceinline__ float bf2f(us h) { return __uint_as_float(((unsigned)h) << 16); }
__device__ __forceinline__ void split2(float q, us& h, us& l) {
    h = f2bf(q); l = f2bf(q - bf2f(h));
}

// exact log-domain fake quant: q = sign(x)*s*2^round(log2(clip(|x|/s,2^-255,1)))
// boundary decided in double (exact vs a float64 reference; unbiased vs float32 log2)
__device__ __forceinline__ float logq_exact(float x, float s) {
    float ax = fabsf(x);
    if (ax >= s) return copysignf(s, x);
    if (ax == 0.f) return copysignf(0.f, x);
    double r = (double)ax / (double)s;
    int ex;
    double mant = frexp(r, &ex);                       // [0.5,1)
    int e = (mant >= 0.70710678118654752440) ? ex : ex - 1;
    e = (e < -255) ? -255 : e;
    return copysignf(ldexpf(s, e), x);
}

__device__ __forceinline__ void gll16(const void* g, void* l) {
    __builtin_amdgcn_global_load_lds(
        (const __attribute__((address_space(1))) void*)g,
        (__attribute__((address_space(3))) void*)l, 16, 0, 0);
}

// ---------------- scales / quant / lora prep ----------------

__global__ void k_zero(unsigned* p, int n) {
    int i = blockIdx.x * 256 + threadIdx.x;
    if (i < n) p[i] = 0u;
}

__global__ void k_colmax(const float* __restrict__ x, unsigned* __restrict__ smax) {
    int c = blockIdx.x * 256 + threadIdx.x;
    int r0 = blockIdx.y * 128;
    float m = 0.f;
    for (int r = 0; r < 128; ++r) m = fmaxf(m, fabsf(x[(size_t)(r0 + r) * DD + c]));
    atomicMax(smax + c, __float_as_uint(m));
}

// one block per row: quantize 1024 cols -> hi/lo bf16; bias col (1040)=1.0; pads 0
__global__ void k_quant_rows(const float* __restrict__ x, const unsigned* __restrict__ smax,
                             us* __restrict__ xh, us* __restrict__ xl) {
    int m = blockIdx.x, tx = threadIdx.x;
    float4 xv = ((const float4*)(x + (size_t)m * DD))[tx];
    int c = tx * 4;
    float vv[4] = {xv.x, xv.y, xv.z, xv.w};
    ushort4 qh, ql;
    us* ph = (us*)&qh; us* pl = (us*)&ql;
#pragma unroll
    for (int j = 0; j < 4; ++j) {
        float s = fmaxf(__uint_as_float(smax[c + j]), 1e-8f);
        float q = logq_exact(vv[j], s);
        split2(q, ph[j], pl[j]);
    }
    *(ushort4*)(xh + (size_t)m * KP + c) = qh;
    *(ushort4*)(xl + (size_t)m * KP + c) = ql;
    if (tx == 0) { xh[(size_t)m * KP + 1040] = 0x3F80; xl[(size_t)m * KP + 1040] = 0; }
    else if (tx < 16) { xh[(size_t)m * KP + 1040 + tx] = 0; xl[(size_t)m * KP + 1040 + tx] = 0; }
}

// one wave per row: lora cols 1024..1039 = split(2 * x@lA)
__global__ void k_lora_x(const float* __restrict__ x, const float* __restrict__ lA,
                         us* __restrict__ xh, us* __restrict__ xl) {
    int w = threadIdx.x >> 6, lane = threadIdx.x & 63;
    int m = blockIdx.x * 4 + w;
    const float* xr = x + (size_t)m * DD;
    float acc[16];
#pragma unroll
    for (int r = 0; r < 16; ++r) acc[r] = 0.f;
#pragma unroll
    for (int i = 0; i < 4; ++i) {
        int c0 = i * 256 + lane * 4;
        float4 xv = *(const float4*)(xr + c0);
        float xs4[4] = {xv.x, xv.y, xv.z, xv.w};
#pragma unroll
        for (int j = 0; j < 4; ++j) {
            float xs = xs4[j];
            const float4* lr = (const float4*)(lA + (size_t)(c0 + j) * 16);
            float4 a0 = lr[0], a1 = lr[1], a2 = lr[2], a3 = lr[3];
            acc[0] += xs * a0.x; acc[1] += xs * a0.y; acc[2] += xs * a0.z; acc[3] += xs * a0.w;
            acc[4] += xs * a1.x; acc[5] += xs * a1.y; acc[6] += xs * a1.z; acc[7] += xs * a1.w;
            acc[8] += xs * a2.x; acc[9] += xs * a2.y; acc[10] += xs * a2.z; acc[11] += xs * a2.w;
            acc[12] += xs * a3.x; acc[13] += xs * a3.y; acc[14] += xs * a3.z; acc[15] += xs * a3.w;
        }
    }
#pragma unroll
    for (int msk = 1; msk < 64; msk <<= 1)
#pragma unroll
        for (int r = 0; r < 16; ++r) acc[r] += __shfl_xor(acc[r], msk);
    if (lane == 0) {
#pragma unroll
        for (int r = 0; r < 16; ++r) {
            us h, l; split2(2.0f * acc[r], h, l);
            xh[(size_t)m * KP + 1024 + r] = h;
            xl[(size_t)m * KP + 1024 + r] = l;
        }
    }
}

// one block per output row n: row scale -> hi/lo quant; lora col split(lB); bias col split(b)
__global__ __launch_bounds__(256) void k_quant_w(const float* __restrict__ W, const float* __restrict__ lB,
                                                 const float* __restrict__ bias,
                                                 us* __restrict__ wh, us* __restrict__ wl, int Nn) {
    __shared__ float red[4];
    int n = blockIdx.x, tx = threadIdx.x;
    int lane = tx & 63, w = tx >> 6;
    float4 wv = ((const float4*)(W + (size_t)n * DD))[tx];
    float m4 = fmaxf(fmaxf(fabsf(wv.x), fabsf(wv.y)), fmaxf(fabsf(wv.z), fabsf(wv.w)));
#pragma unroll
    for (int msk = 1; msk < 64; msk <<= 1) m4 = fmaxf(m4, __shfl_xor(m4, msk));
    if (lane == 0) red[w] = m4;
    __syncthreads();
    float s = fmaxf(fmaxf(fmaxf(red[0], red[1]), fmaxf(red[2], red[3])), 1e-8f);
    float vv[4] = {wv.x, wv.y, wv.z, wv.w};
    ushort4 qh, ql;
    us* ph = (us*)&qh; us* pl = (us*)&ql;
#pragma unroll
    for (int j = 0; j < 4; ++j) {
        float q = logq_exact(vv[j], s);
        split2(q, ph[j], pl[j]);
    }
    *(ushort4*)(wh + (size_t)n * KP + tx * 4) = qh;
    *(ushort4*)(wl + (size_t)n * KP + tx * 4) = ql;
    if (tx < 16) {
        us h, l; split2(lB[(size_t)tx * Nn + n], h, l);
        wh[(size_t)n * KP + 1024 + tx] = h; wl[(size_t)n * KP + 1024 + tx] = l;
    } else if (tx < 32) {
        us h = 0, l = 0;
        if (tx == 16) split2(bias[n], h, l);
        wh[(size_t)n * KP + 1024 + tx] = h; wl[(size_t)n * KP + 1024 + tx] = l;
    }
}

// ---------------- GEMM: C = (Ah+Al)(Bh+Bl)^T via 3 MFMA passes, fp32 out ----------------
// SPLIT3: output goes to [3][8192][1024] planes (qkv); else linear [M][Nn]

template <int SPLIT3>
__global__ __launch_bounds__(256) void k_gemm(const us* __restrict__ Ah_, const us* __restrict__ Al_,
                                              const us* __restrict__ Bh_, const us* __restrict__ Bl_,
                                              float* __restrict__ C, int Nn) {
    __shared__ us AhL[4096], AlL[4096], BhL[4096], BlL[4096];   // [128][32] each
    int tid = threadIdx.x;
    int bm = blockIdx.x, bn = blockIdx.y;
    int lane = tid & 63, w = tid >> 6;
    int wm = w >> 1, wn = w & 1;
    int l15 = lane & 15, l4 = lane >> 4;
    size_t aoff = ((size_t)bm * 128 + (tid >> 2)) * KP + (tid & 3) * 8;
    size_t boff = ((size_t)bn * 128 + (tid >> 2)) * KP + (tid & 3) * 8;
    f32x4 zero4 = {0.f, 0.f, 0.f, 0.f};
    f32x4 acc[4][4];
#pragma unroll
    for (int i = 0; i < 4; ++i)
#pragma unroll
        for (int j = 0; j < 4; ++j) acc[i][j] = zero4;

    for (int kt = 0; kt < KP / 32; ++kt) {
        int k0 = kt * 32;
        __syncthreads();
        gll16(Ah_ + aoff + k0, AhL + tid * 8);
        gll16(Ah_ + aoff + (size_t)64 * KP + k0, AhL + 2048 + tid * 8);
        gll16(Al_ + aoff + k0, AlL + tid * 8);
        gll16(Al_ + aoff + (size_t)64 * KP + k0, AlL + 2048 + tid * 8);
        gll16(Bh_ + boff + k0, BhL + tid * 8);
        gll16(Bh_ + boff + (size_t)64 * KP + k0, BhL + 2048 + tid * 8);
        gll16(Bl_ + boff + k0, BlL + tid * 8);
        gll16(Bl_ + boff + (size_t)64 * KP + k0, BlL + 2048 + tid * 8);
        __syncthreads();
        bf16x8 ah[4], al[4], bh[4], bl[4];
#pragma unroll
        for (int i = 0; i < 4; ++i) {
            int ro = (wm * 64 + i * 16 + l15) * 32 + l4 * 8;
            int co = (wn * 64 + i * 16 + l15) * 32 + l4 * 8;
            ah[i] = *(const bf16x8*)(AhL + ro);
            al[i] = *(const bf16x8*)(AlL + ro);
            bh[i] = *(const bf16x8*)(BhL + co);
            bl[i] = *(const bf16x8*)(BlL + co);
        }
#pragma unroll
        for (int mi = 0; mi < 4; ++mi)
#pragma unroll
            for (int ni = 0; ni < 4; ++ni) {
                acc[mi][ni] = __builtin_amdgcn_mfma_f32_16x16x32_bf16(ah[mi], bh[ni], acc[mi][ni], 0, 0, 0);
                acc[mi][ni] = __builtin_amdgcn_mfma_f32_16x16x32_bf16(ah[mi], bl[ni], acc[mi][ni], 0, 0, 0);
                acc[mi][ni] = __builtin_amdgcn_mfma_f32_16x16x32_bf16(al[mi], bh[ni], acc[mi][ni], 0, 0, 0);
            }
    }
#pragma unroll
    for (int mi = 0; mi < 4; ++mi) {
#pragma unroll
        for (int ni = 0; ni < 4; ++ni) {
            int ncol = bn * 128 + wn * 64 + ni * 16 + l15;
            size_t mbase = (size_t)bm * 128 + wm * 64 + mi * 16 + l4 * 4;
#pragma unroll
            for (int rr = 0; rr < 4; ++rr) {
                float v = acc[mi][ni][rr];
                if (SPLIT3) {
                    size_t plane = (size_t)(ncol >> 10);
                    C[plane * QKSZ + (mbase + rr) * DD + (ncol & 1023)] = v;
                } else {
                    C[(mbase + rr) * (size_t)Nn + ncol] = v;
                }
            }
        }
    }
}

// ---------------- V transpose+split: vbuf f32 [b*S+s][h*64+hd] -> vth/vtl [bh][hd][s] bf16 ----------------

__global__ __launch_bounds__(256) void k_transpose_v(const float* __restrict__ vbuf,
                                                     us* __restrict__ vth, us* __restrict__ vtl) {
    __shared__ us th[64][68], tl[64][68];
    int st = blockIdx.x, bh = blockIdx.y;
    int b = bh >> 4, h = bh & 15;
    int s0 = st * 64, tid = threadIdx.x;
#pragma unroll
    for (int p = 0; p < 2; ++p) {
        int sl = p * 32 + (tid >> 3);
        int hd0 = (tid & 7) * 8;
        const float* src = vbuf + (size_t)(b * SS + s0 + sl) * DD + h * 64 + hd0;
        float4 v0 = *(const float4*)src;
        float4 v1 = *(const float4*)(src + 4);
        float vv[8] = {v0.x, v0.y, v0.z, v0.w, v1.x, v1.y, v1.z, v1.w};
#pragma unroll
        for (int j = 0; j < 8; ++j) {
            us hq, lq; split2(vv[j], hq, lq);
            th[hd0 + j][sl] = hq; tl[hd0 + j][sl] = lq;
        }
    }
    __syncthreads();
#pragma unroll
    for (int p = 0; p < 2; ++p) {
        int hd = p * 32 + (tid >> 3);
        int sc = (tid & 7) * 8;
        size_t dof = ((size_t)bh * 64 + hd) * SS + s0 + sc;
        *(ushort4*)(vth + dof) = *(const ushort4*)&th[hd][sc];
        *(ushort4*)(vth + dof + 4) = *(const ushort4*)&th[hd][sc + 4];
        *(ushort4*)(vtl + dof) = *(const ushort4*)&tl[hd][sc];
        *(ushort4*)(vtl + dof + 4) = *(const ushort4*)&tl[hd][sc + 4];
    }
}

// ---------------- causal flash attention, hi/lo split Q,K,V,P ----------------
// grid (64 bh, 16 qt rev), 4 waves; wave owns 32 q rows; KV tiles of 32.
// Swapped QK^T: sf = mfma(K,Q) -> lane l15 = q row; D rows = kv = l4*4+rr (+16*kb).

__global__ __launch_bounds__(256) void k_attn(const float* __restrict__ qbuf,
                                              const float* __restrict__ kbuf,
                                              const us* __restrict__ vth_g,
                                              const us* __restrict__ vtl_g,
                                              float* __restrict__ o) {
    __shared__ float Ks[2048];     // [32 kv][64 hd] f32, 16B-granule XOR-16 swizzle
    __shared__ us Vh[2048], Vl[2048];  // [64 hd][32 kv] bf16, 16B-granule XOR-4 swizzle
    int bh = blockIdx.x;
    int qt = (int)(gridDim.y - 1) - blockIdx.y;
    int b = bh >> 4, h = bh & 15;
    int q0 = qt * 128;
    int tid = threadIdx.x, w = tid >> 6, lane = tid & 63;
    int l15 = lane & 15, l4 = lane >> 4;
    int qw = q0 + w * 32;

    // Q fragments: fp32 load -> hi/lo split
    bf16x8 qh[2][2], ql[2][2];
#pragma unroll
    for (int qb = 0; qb < 2; ++qb)
#pragma unroll
        for (int hf = 0; hf < 2; ++hf) {
            const float* qp = qbuf + (size_t)(b * SS + qw + qb * 16 + l15) * DD + h * 64 + hf * 32 + l4 * 8;
            float4 a = *(const float4*)qp;
            float4 c = *(const float4*)(qp + 4);
            float vv[8] = {a.x, a.y, a.z, a.w, c.x, c.y, c.z, c.w};
            bf16x8 hq, lq;
#pragma unroll
            for (int j = 0; j < 8; ++j) {
                us hh = f2bf(vv[j]);
                hq[j] = (short)hh;
                lq[j] = (short)f2bf(vv[j] - bf2f(hh));
            }
            qh[qb][hf] = hq; ql[qb][hf] = lq;
        }

    f32x4 zero4 = {0.f, 0.f, 0.f, 0.f};
    f32x4 of[2][4];
#pragma unroll
    for (int i = 0; i < 2; ++i)
#pragma unroll
        for (int j = 0; j < 4; ++j) of[i][j] = zero4;
    float mrow[2] = {-1e30f, -1e30f}, lrow[2] = {0.f, 0.f};

    // staging index precompute
    int kr0 = tid >> 4, kj0 = (tid & 15) ^ (kr0 & 15);
    int kr1 = (tid + 256) >> 4, kj1 = ((tid + 256) & 15) ^ (kr1 & 15);
    int vr = tid >> 2, vj = (tid & 3) ^ (vr & 3);
    const float* kb0 = kbuf + (size_t)(b * SS + kr0) * DD + h * 64 + kj0 * 4;
    const float* kb1 = kbuf + (size_t)(b * SS + kr1) * DD + h * 64 + kj1 * 4;
    const us* vhb = vth_g + ((size_t)bh * 64 + vr) * SS + vj * 8;
    const us* vlb = vtl_g + ((size_t)bh * 64 + vr) * SS + vj * 8;

    int ntiles = q0 / 32 + 4;
    for (int t = 0; t < ntiles; ++t) {
        int kv0 = t * 32;
        __syncthreads();
        gll16(kb0 + (size_t)kv0 * DD, (char*)Ks + tid * 16);
        gll16(kb1 + (size_t)kv0 * DD, (char*)Ks + 4096 + tid * 16);
        gll16(vhb + kv0, (char*)Vh + tid * 16);
        gll16(vlb + kv0, (char*)Vl + tid * 16);
        __syncthreads();
        if (kv0 > qw + 31) continue;

        // QK^T with hi/lo split (3 mfma per operand pair)
        f32x4 sf[2][2];
#pragma unroll
        for (int i = 0; i < 2; ++i)
#pragma unroll
            for (int j = 0; j < 2; ++j) sf[i][j] = zero4;
#pragma unroll
        for (int hf = 0; hf < 2; ++hf)
#pragma unroll
            for (int kb = 0; kb < 2; ++kb) {
                int r = kb * 16 + l15;
                int g0 = hf * 8 + l4 * 2;
                f32x4 x0 = *(const f32x4*)(Ks + r * 64 + ((g0) ^ (r & 15)) * 4);
                f32x4 x1 = *(const f32x4*)(Ks + r * 64 + ((g0 + 1) ^ (r & 15)) * 4);
                float vv[8] = {x0[0], x0[1], x0[2], x0[3], x1[0], x1[1], x1[2], x1[3]};
                bf16x8 kh, kl;
#pragma unroll
                for (int j = 0; j < 8; ++j) {
                    us hh = f2bf(vv[j]);
                    kh[j] = (short)hh;
                    kl[j] = (short)f2bf(vv[j] - bf2f(hh));
                }
#pragma unroll
                for (int qb = 0; qb < 2; ++qb) {
                    sf[kb][qb] = __builtin_amdgcn_mfma_f32_16x16x32_bf16(kh, qh[qb][hf], sf[kb][qb], 0, 0, 0);
                    sf[kb][qb] = __builtin_amdgcn_mfma_f32_16x16x32_bf16(kh, ql[qb][hf], sf[kb][qb], 0, 0, 0);
                    sf[kb][qb] = __builtin_amdgcn_mfma_f32_16x16x32_bf16(kl, qh[qb][hf], sf[kb][qb], 0, 0, 0);
                }
            }

        // softmax per qb -> ph/pl, rescale of
        bf16x8 ph[2], pl[2];
#pragma unroll
        for (int qb = 0; qb < 2; ++qb) {
            int qg = qw + qb * 16 + l15;
            float pv[8];
            float tmax = -1e30f;
#pragma unroll
            for (int kb = 0; kb < 2; ++kb)
#pragma unroll
                for (int rr = 0; rr < 4; ++rr) {
                    int kvg = kv0 + kb * 16 + l4 * 4 + rr;
                    float sc = sf[kb][qb][rr] * 0.125f;
                    sc = (kvg > qg) ? -1e30f : sc;
                    pv[kb * 4 + rr] = sc;
                    tmax = fmaxf(tmax, sc);
                }
            tmax = fmaxf(tmax, __shfl_xor(tmax, 16));
            tmax = fmaxf(tmax, __shfl_xor(tmax, 32));
            float mnew = fmaxf(mrow[qb], tmax);
            float fac = __expf(mrow[qb] - mnew);
            mrow[qb] = mnew;
            float ps = 0.f;
#pragma unroll
            for (int i = 0; i < 8; ++i) { pv[i] = __expf(pv[i] - mnew); ps += pv[i]; }
            ps += __shfl_xor(ps, 16); ps += __shfl_xor(ps, 32);
            lrow[qb] = lrow[qb] * fac + ps;
            bf16x8 hq, lq;
#pragma unroll
            for (int i = 0; i < 8; ++i) {
                us hh = f2bf(pv[i]);
                hq[i] = (short)hh;
                lq[i] = (short)f2bf(pv[i] - bf2f(hh));
            }
            ph[qb] = hq; pl[qb] = lq;
            float fr0 = __shfl(fac, l4 * 4 + 0);
            float fr1 = __shfl(fac, l4 * 4 + 1);
            float fr2 = __shfl(fac, l4 * 4 + 2);
            float fr3 = __shfl(fac, l4 * 4 + 3);
#pragma unroll
            for (int hb = 0; hb < 4; ++hb) {
                of[qb][hb][0] *= fr0; of[qb][hb][1] *= fr1;
                of[qb][hb][2] *= fr2; of[qb][hb][3] *= fr3;
            }
        }

        // PV with hi/lo split
#pragma unroll
        for (int hb = 0; hb < 4; ++hb) {
            int r = hb * 16 + l15;
            const us* vph = Vh + r * 32 + (l4 & 1) * 4;
            const us* vpl = Vl + r * 32 + (l4 & 1) * 4;
            int ga = ((l4 >> 1) ^ (r & 3)) * 8;
            int gb2 = (((l4 >> 1) + 2) ^ (r & 3)) * 8;
            bf16x4v hlo = *(const bf16x4v*)(vph + ga);
            bf16x4v hhi = *(const bf16x4v*)(vph + gb2);
            bf16x4v llo = *(const bf16x4v*)(vpl + ga);
            bf16x4v lhi = *(const bf16x4v*)(vpl + gb2);
            bf16x8 vh, vl;
#pragma unroll
            for (int j = 0; j < 4; ++j) {
                vh[j] = hlo[j]; vh[4 + j] = hhi[j];
                vl[j] = llo[j]; vl[4 + j] = lhi[j];
            }
#pragma unroll
            for (int qb = 0; qb < 2; ++qb) {
                of[qb][hb] = __builtin_amdgcn_mfma_f32_16x16x32_bf16(ph[qb], vh, of[qb][hb], 0, 0, 0);
                of[qb][hb] = __builtin_amdgcn_mfma_f32_16x16x32_bf16(ph[qb], vl, of[qb][hb], 0, 0, 0);
                of[qb][hb] = __builtin_amdgcn_mfma_f32_16x16x32_bf16(pl[qb], vh, of[qb][hb], 0, 0, 0);
            }
        }
    }

#pragma unroll
    for (int qb = 0; qb < 2; ++qb) {
        float linv = 1.f / lrow[qb];
        float f0 = __shfl(linv, l4 * 4 + 0);
        float f1 = __shfl(linv, l4 * 4 + 1);
        float f2 = __shfl(linv, l4 * 4 + 2);
        float f3 = __shfl(linv, l4 * 4 + 3);
        int qgb = qw + qb * 16 + l4 * 4;
#pragma unroll
        for (int hb = 0; hb < 4; ++hb) {
            int col = h * 64 + hb * 16 + l15;
            o[((size_t)(b * SS + qgb + 0)) * DD + col] = of[qb][hb][0] * f0;
            o[((size_t)(b * SS + qgb + 1)) * DD + col] = of[qb][hb][1] * f1;
            o[((size_t)(b * SS + qgb + 2)) * DD + col] = of[qb][hb][2] * f2;
            o[((size_t)(b * SS + qgb + 3)) * DD + col] = of[qb][hb][3] * f3;
        }
    }
}

// ---------------- launcher ----------------

extern "C" void kernel_launch(void* const* d_in, const int* in_sizes, int n_in,
                              void* d_out, int out_size, void* d_ws, size_t ws_size,
                              hipStream_t stream) {
    const float* hidden  = (const float*)d_in[0];
    const float* W_attn  = (const float*)d_in[2];
    const float* b_attn  = (const float*)d_in[3];
    const float* lA_attn = (const float*)d_in[4];
    const float* lB_attn = (const float*)d_in[5];
    const float* W_proj  = (const float*)d_in[6];
    const float* b_proj  = (const float*)d_in[7];
    const float* lA_proj = (const float*)d_in[8];
    const float* lB_proj = (const float*)d_in[9];
    float* out = (float*)d_out;

    char* ws = (char*)d_ws;
    unsigned* s1 = (unsigned*)(ws);
    unsigned* s2 = (unsigned*)(ws + 4096);
    us* xh  = (us*)(ws + 8192);                        // 17,301,504
    us* xl  = (us*)(ws + 8192 + 17301504);             // 17,301,504
    us* vth = (us*)(ws + 8192);                        // overlay on xh/xl (phase B only)
    us* vtl = (us*)(ws + 8192 + 16777216);
    char* wbase = ws + 8192 + 2 * 17301504;            // 34,611,200
    us* wh1 = (us*)(wbase);
    us* wl1 = (us*)(wbase + 6488064);
    us* wh2 = (us*)(wbase + 2 * 6488064);
    us* wl2 = (us*)(wbase + 2 * 6488064 + 2162688);
    float* qkv3 = (float*)(wbase + 2 * 6488064 + 2 * 2162688);  // 3 planes f32
    float* qbuf = qkv3;
    float* kbuf = qkv3 + QKSZ;
    float* vbuf = qkv3 + 2 * QKSZ;
    float* attn = vbuf;                                // overlay: v plane consumed by transpose

    k_zero<<<8, 256, 0, stream>>>(s1, 2048);

    // ---- qkv projection ----
    k_colmax<<<dim3(4, 64), 256, 0, stream>>>(hidden, s1);
    k_quant_rows<<<MTOT, 256, 0, stream>>>(hidden, s1, xh, xl);
    k_lora_x<<<MTOT / 4, 256, 0, stream>>>(hidden, lA_attn, xh, xl);
    k_quant_w<<<3072, 256, 0, stream>>>(W_attn, lB_attn, b_attn, wh1, wl1, 3072);
    k_quant_w<<<1024, 256, 0, stream>>>(W_proj, lB_proj, b_proj, wh2, wl2, 1024);
    k_gemm<1><<<dim3(64, 24), 256, 0, stream>>>(xh, xl, wh1, wl1, qkv3, DQKV);

    // ---- attention ----
    k_transpose_v<<<dim3(32, 64), 256, 0, stream>>>(vbuf, vth, vtl);
    k_attn<<<dim3(64, 16), 256, 0, stream>>>(qbuf, kbuf, vth, vtl, attn);

    // ---- output projection ----
    k_colmax<<<dim3(4, 64), 256, 0, stream>>>(attn, s2);
    k_quant_rows<<<MTOT, 256, 0, stream>>>(attn, s2, xh, xl);
    k_lora_x<<<MTOT / 4, 256, 0, stream>>>(attn, lA_proj, xh, xl);
    k_gemm<0><<<dim3(64, 8), 256, 0, stream>>>(xh, xl, wh2, wl2, out, DD);
}